// Round 6
// baseline (304.154 us; speedup 1.0000x reference)
//
#include <hip/hip_runtime.h>

typedef _Float16 f16_t;
typedef _Float16 f16x4 __attribute__((ext_vector_type(4)));
typedef _Float16 f16x8 __attribute__((ext_vector_type(8)));
typedef float f32x4 __attribute__((ext_vector_type(4)));

#define D_MODEL 1024
#define LSEQ 4096
#define NH 16
#define DH 64
// (1/sqrt(64)) * log2(e), folded into Wq so scores feed v_exp_f32 (base-2) directly
#define QSCALE 0.18033688011112042f

#define GLDS16(g, l)                                                     \
    __builtin_amdgcn_global_load_lds(                                    \
        (const __attribute__((address_space(1))) void*)(g),              \
        (__attribute__((address_space(3))) void*)(l), 16, 0, 0)

// Partial drains: each wave waits until at most N of ITS vmem ops remain.
// Deposits that have landed are visible CU-wide in LDS; the following
// __syncthreads makes every wave's landed deposits visible to all.
#define WAIT_VM(n) asm volatile("s_waitcnt vmcnt(" #n ")" ::: "memory")

// ---------------- fp32 -> fp16 conversion ----------------
__global__ __launch_bounds__(256) void cvt_x(const float* __restrict__ in,
                                             f16_t* __restrict__ out, int n) {
    int i = (blockIdx.x * 256 + threadIdx.x) * 4;
    if (i + 3 < n) {
        float4 v = *(const float4*)&in[i];
        alignas(8) f16_t o4[4] = {(f16_t)v.x, (f16_t)v.y, (f16_t)v.z, (f16_t)v.w};
        *(uint2*)&out[i] = *(const uint2*)o4;
    }
}

// all 4 weights in one launch; Wq gets QSCALE folded in
__global__ __launch_bounds__(256) void cvt_w4(const float* __restrict__ w0,
                                              const float* __restrict__ w1,
                                              const float* __restrict__ w2,
                                              const float* __restrict__ w3,
                                              f16_t* __restrict__ out) {
    const int q = blockIdx.y;
    const float* src = (q == 0) ? w0 : (q == 1) ? w1 : (q == 2) ? w2 : w3;
    const float scale = (q == 0) ? QSCALE : 1.f;
    int i = (blockIdx.x * 256 + threadIdx.x) * 4;
    float4 v = *(const float4*)&src[i];
    alignas(8) f16_t o4[4] = {(f16_t)(v.x * scale), (f16_t)(v.y * scale),
                              (f16_t)(v.z * scale), (f16_t)(v.w * scale)};
    *(uint2*)&out[(size_t)q * (D_MODEL * D_MODEL) + i] = *(const uint2*)o4;
}

// ---------------- fp16 GEMM: C = A @ B^T ----------------
// Tile 128x128, BK=32, 4 waves. Triple-buffered fragment-major LDS staging with
// prefetch depth 2: at iter kt, stage(kt+1) stays in flight (vmcnt(4)) while
// buffer kt is consumed -> HBM latency (~900cyc) covered by ~2 tiles of work.
// mode 0: out f16 head-split [(col>>6)][M][64]; mode 1: out fp32 [M][N]
__global__ __launch_bounds__(256, 3) void gemm_f16(const f16_t* __restrict__ A,
                                                   const f16_t* __restrict__ B,
                                                   void* __restrict__ Cout,
                                                   int M, int N, int K, int mode) {
    __shared__ alignas(16) f16_t As[3][128 * 32];
    __shared__ alignas(16) f16_t Bs[3][128 * 32];

    const int tid  = threadIdx.x;
    const int wave = tid >> 6;
    const int lane = tid & 63;
    const int quad = lane >> 4;
    const int l16  = lane & 15;
    const int wm = (wave & 1) * 64;
    const int wn = (wave >> 1) * 64;
    const int bm = blockIdx.x * 128;
    const int bn = blockIdx.y * 128;

    f32x4 acc[4][4] = {};
    const int nk = K / 32;

    auto stage = [&](int kt, int b) {  // 4 GLDS per wave
        const int c0 = wave * 2;
        GLDS16(&A[(size_t)(bm + c0 * 16 + l16) * K + kt * 32 + quad * 8],
               &As[b][c0 * 512]);
        GLDS16(&A[(size_t)(bm + (c0 + 1) * 16 + l16) * K + kt * 32 + quad * 8],
               &As[b][(c0 + 1) * 512]);
        GLDS16(&B[(size_t)(bn + c0 * 16 + l16) * K + kt * 32 + quad * 8],
               &Bs[b][c0 * 512]);
        GLDS16(&B[(size_t)(bn + (c0 + 1) * 16 + l16) * K + kt * 32 + quad * 8],
               &Bs[b][(c0 + 1) * 512]);
    };

    stage(0, 0);
    stage(1, 1);
    for (int kt = 0; kt < nk; ++kt) {
        const int cb = kt % 3;
        // entering: stage(kt)[4] + stage(kt+1)[4] outstanding (per wave).
        if (kt < nk - 1) WAIT_VM(4);   // stage(kt) landed; kt+1 keeps flying
        else             WAIT_VM(0);
        __syncthreads();
        if (kt + 2 < nk) stage(kt + 2, (kt + 2) % 3);

        f16x8 af[4], bfr[4];
#pragma unroll
        for (int mt = 0; mt < 4; ++mt)
            af[mt] = *(const f16x8*)&As[cb][((wm >> 4) + mt) * 512 + lane * 8];
#pragma unroll
        for (int nt = 0; nt < 4; ++nt)
            bfr[nt] = *(const f16x8*)&Bs[cb][((wn >> 4) + nt) * 512 + lane * 8];
#pragma unroll
        for (int mt = 0; mt < 4; ++mt)
#pragma unroll
            for (int nt = 0; nt < 4; ++nt)
                acc[mt][nt] = __builtin_amdgcn_mfma_f32_16x16x32_f16(
                    af[mt], bfr[nt], acc[mt][nt], 0, 0, 0);
        // buffer cb is not re-staged until stage(kt+3), which is issued after
        // the NEXT barrier; __syncthreads drains lgkmcnt -> reads are complete.
    }

#pragma unroll
    for (int mt = 0; mt < 4; ++mt)
#pragma unroll
        for (int nt = 0; nt < 4; ++nt)
#pragma unroll
            for (int r = 0; r < 4; ++r) {
                int row = bm + wm + mt * 16 + quad * 4 + r;
                int col = bn + wn + nt * 16 + l16;
                float v = acc[mt][nt][r];
                if (mode == 0) {
                    ((f16_t*)Cout)[((size_t)(col >> 6) * M + row) * 64 + (col & 63)] =
                        (f16_t)v;
                } else {
                    ((float*)Cout)[(size_t)row * N + col] = v;
                }
            }
}

// ---------------- V transpose: vh[H][L][64] -> vt[H][64][L] ----------------
__global__ __launch_bounds__(256) void transpose_v(const f16_t* __restrict__ vh,
                                                   f16_t* __restrict__ vt) {
    __shared__ f16_t Ts[64][72];
    const int t = threadIdx.x;
    const int lt = blockIdx.x;
    const int head = blockIdx.y;

#pragma unroll
    for (int i = 0; i < 2; ++i) {
        int idx = t + i * 256;
        int row = idx >> 3, part = idx & 7;
        *(uint4*)&Ts[row][part * 8] =
            *(const uint4*)&vh[((size_t)head * LSEQ + lt * 64 + row) * DH + part * 8];
    }
    __syncthreads();
#pragma unroll
    for (int i = 0; i < 2; ++i) {
        int idx = t + i * 256;
        int d = idx >> 3, part = idx & 7;
        alignas(16) f16_t p8[8];
#pragma unroll
        for (int j = 0; j < 8; ++j) p8[j] = Ts[part * 8 + j][d];
        *(uint4*)&vt[((size_t)head * DH + d) * LSEQ + lt * 64 + part * 8] =
            *(const uint4*)p8;
    }
}

// ---------------- attention ----------------
// qh/kh: [NH][L][64] f16 (Q pre-scaled), vt: [NH][64][L] f16, ao: [L][1024] f16
// S^T formulation. 64 q-rows per wave (qt=0..3): kf/vf LDS reads amortize over
// 2x MFMAs vs R5 (ratio 64 MFMA : 28 b128). Triple-buffered K/V staging,
// prefetch depth 2, vmcnt(4) partial drains. Grid 256 = 1 block/CU, 4 waves.
__global__ __launch_bounds__(256, 1) void attn_kernel(const f16_t* __restrict__ qh,
                                                      const f16_t* __restrict__ kh,
                                                      const f16_t* __restrict__ vt,
                                                      f16_t* __restrict__ ao) {
    __shared__ alignas(16) f16_t Ks[3][8 * 512];  // chunk j=mt*2+kc, frag-major
    __shared__ alignas(16) f16_t Vs[3][8 * 512];  // chunk j=dt*2+kc, frag-major
    __shared__ alignas(16) f16_t Ps[4][64][72];   // per-wave P^T [qrow][key]

    const int tid  = threadIdx.x;
    const int wave = tid >> 6;
    const int lane = tid & 63;
    const int quad = lane >> 4;
    const int l16  = lane & 15;

    // XCD swizzle: 2 heads per XCD (per-XCD K/V+Vt working set ~2MB < 4MB L2)
    const int id = blockIdx.x;
    const int head = (id & 7) * 2 + ((id >> 3) & 1);
    const int qrow0 = (id >> 4) * 256 + wave * 64;

    const f16_t* Q  = qh + (size_t)head * LSEQ * DH;
    const f16_t* K  = kh + (size_t)head * LSEQ * DH;
    const f16_t* Vt = vt + (size_t)head * DH * LSEQ;

    // Q as B-operand, 64 q-rows in registers (32 VGPRs)
    f16x8 qf[4][2];
#pragma unroll
    for (int qt = 0; qt < 4; ++qt)
#pragma unroll
        for (int kc = 0; kc < 2; ++kc)
            qf[qt][kc] = *(const f16x8*)
                &Q[(size_t)(qrow0 + qt * 16 + l16) * DH + kc * 32 + quad * 8];

    f32x4 o[4][4] = {};      // O^T accum [d-tile][q-tile]
    float lp[4] = {0.f, 0.f, 0.f, 0.f};

    auto stage = [&](int kt, int b) {  // 4 GLDS per wave
        const int j0 = wave * 2;
#pragma unroll
        for (int jj = 0; jj < 2; ++jj) {
            const int j = j0 + jj, mt = j >> 1, kc = j & 1;
            GLDS16(&K[(size_t)(kt * 64 + mt * 16 + l16) * DH + kc * 32 + quad * 8],
                   &Ks[b][j * 512]);
            GLDS16(&Vt[(size_t)(mt * 16 + l16) * LSEQ + kt * 64 + kc * 32 + quad * 8],
                   &Vs[b][j * 512]);
        }
    };

    const int NT = LSEQ / 64;
    stage(0, 0);
    stage(1, 1);
    for (int kt = 0; kt < NT; ++kt) {
        const int cb = kt % 3;
        if (kt < NT - 1) WAIT_VM(4);   // stage(kt) landed; kt+1 keeps flying
        else             WAIT_VM(0);
        __syncthreads();
        if (kt + 2 < NT) stage(kt + 2, (kt + 2) % 3);

        f16x8 kf[4][2], vf[4][2];
#pragma unroll
        for (int mt = 0; mt < 4; ++mt)
#pragma unroll
            for (int kc = 0; kc < 2; ++kc)
                kf[mt][kc] = *(const f16x8*)&Ks[cb][(mt * 2 + kc) * 512 + lane * 8];
#pragma unroll
        for (int dt = 0; dt < 4; ++dt)
#pragma unroll
            for (int kc = 0; kc < 2; ++kc)
                vf[dt][kc] = *(const f16x8*)&Vs[cb][(dt * 2 + kc) * 512 + lane * 8];

        // S^T = K_tile . Q^T : D[m=key][n=qrow], 32 MFMA
        f32x4 s[4][4] = {};
#pragma unroll
        for (int mt = 0; mt < 4; ++mt)
#pragma unroll
            for (int qt = 0; qt < 4; ++qt)
#pragma unroll
                for (int kc = 0; kc < 2; ++kc)
                    s[mt][qt] = __builtin_amdgcn_mfma_f32_16x16x32_f16(
                        kf[mt][kc], qf[qt][kc], s[mt][qt], 0, 0, 0);

        // exp2 (scale pre-folded), partial row sums, pack P^T (key-minor b64)
#pragma unroll
        for (int mt = 0; mt < 4; ++mt)
#pragma unroll
            for (int qt = 0; qt < 4; ++qt) {
                float e0 = __builtin_amdgcn_exp2f(s[mt][qt][0]);
                float e1 = __builtin_amdgcn_exp2f(s[mt][qt][1]);
                float e2 = __builtin_amdgcn_exp2f(s[mt][qt][2]);
                float e3 = __builtin_amdgcn_exp2f(s[mt][qt][3]);
                lp[qt] += (e0 + e1) + (e2 + e3);
                f16x4 p = {(f16_t)e0, (f16_t)e1, (f16_t)e2, (f16_t)e3};
                *(f16x4*)&Ps[wave][qt * 16 + l16][mt * 16 + quad * 4] = p;
            }
        __builtin_amdgcn_wave_barrier();  // per-wave DS in-order (R2/R5-proven)

        f16x8 pf[4][2];
#pragma unroll
        for (int qt = 0; qt < 4; ++qt)
#pragma unroll
            for (int kc = 0; kc < 2; ++kc)
                pf[qt][kc] = *(const f16x8*)
                    &Ps[wave][qt * 16 + l16][kc * 32 + quad * 8];

        // O^T += V^T . P^T, 32 MFMA
#pragma unroll
        for (int dt = 0; dt < 4; ++dt)
#pragma unroll
            for (int qt = 0; qt < 4; ++qt)
#pragma unroll
                for (int kc = 0; kc < 2; ++kc)
                    o[dt][qt] = __builtin_amdgcn_mfma_f32_16x16x32_f16(
                        vf[dt][kc], pf[qt][kc], o[dt][qt], 0, 0, 0);
        __builtin_amdgcn_wave_barrier();  // next-iter Ps stores stay behind reads
    }

#pragma unroll
    for (int qt = 0; qt < 4; ++qt) {
        float t = lp[qt];
        t += __shfl_xor(t, 16, 64);
        t += __shfl_xor(t, 32, 64);
        lp[qt] = 1.f / t;
    }
#pragma unroll
    for (int dt = 0; dt < 4; ++dt)
#pragma unroll
        for (int qt = 0; qt < 4; ++qt) {
            f16x4 ov = {(f16_t)(o[dt][qt][0] * lp[qt]),
                        (f16_t)(o[dt][qt][1] * lp[qt]),
                        (f16_t)(o[dt][qt][2] * lp[qt]),
                        (f16_t)(o[dt][qt][3] * lp[qt])};
            int qrow = qrow0 + qt * 16 + l16;
            *(f16x4*)&ao[(size_t)qrow * D_MODEL + head * 64 + dt * 16 + quad * 4] = ov;
        }
}

extern "C" void kernel_launch(void* const* d_in, const int* in_sizes, int n_in,
                              void* d_out, int out_size, void* d_ws, size_t ws_size,
                              hipStream_t stream) {
    const float* x  = (const float*)d_in[0];
    const float* Wq = (const float*)d_in[1];
    const float* Wk = (const float*)d_in[2];
    const float* Wv = (const float*)d_in[3];
    const float* Wo = (const float*)d_in[4];

    f16_t* xb = (f16_t*)d_ws;                        // [4096][1024]
    f16_t* wq = xb + (size_t)LSEQ * D_MODEL;         // [3072][1024] qkv concat
    f16_t* wo = wq + (size_t)3 * D_MODEL * D_MODEL;  // [1024][1024]
    f16_t* qh = wo + (size_t)D_MODEL * D_MODEL;      // [16][4096][64]
    f16_t* kh = qh + (size_t)LSEQ * D_MODEL;
    f16_t* vh = kh + (size_t)LSEQ * D_MODEL;
    f16_t* vt = vh + (size_t)LSEQ * D_MODEL;         // [16][64][4096]
    f16_t* ao = vt + (size_t)LSEQ * D_MODEL;         // [4096][1024]

    const int nx = LSEQ * D_MODEL;
    cvt_x<<<nx / 1024, 256, 0, stream>>>(x, xb, nx);
    cvt_w4<<<dim3(D_MODEL * D_MODEL / 1024, 4), 256, 0, stream>>>(Wq, Wk, Wv, Wo, wq);

    // fused QKV projection: [4096][1024] @ [3072][1024]^T -> head-split qh|kh|vh
    gemm_f16<<<dim3(LSEQ / 128, 3 * D_MODEL / 128), 256, 0, stream>>>(
        xb, wq, qh, LSEQ, 3 * D_MODEL, D_MODEL, 0);

    transpose_v<<<dim3(LSEQ / 64, NH), 256, 0, stream>>>(vh, vt);

    attn_kernel<<<dim3((LSEQ / 256) * NH), 256, 0, stream>>>(qh, kh, vt, ao);

    gemm_f16<<<dim3(LSEQ / 128, D_MODEL / 128), 256, 0, stream>>>(
        ao, wo, d_out, LSEQ, D_MODEL, D_MODEL, 1);
}

// Round 7
// 259.747 us; speedup vs baseline: 1.1710x; 1.1710x over previous
//
#include <hip/hip_runtime.h>

typedef _Float16 f16_t;
typedef _Float16 f16x4 __attribute__((ext_vector_type(4)));
typedef _Float16 f16x8 __attribute__((ext_vector_type(8)));
typedef float f32x4 __attribute__((ext_vector_type(4)));

#define D_MODEL 1024
#define LSEQ 4096
#define NH 16
#define DH 64
// (1/sqrt(64)) * log2(e), folded into Wq so scores feed v_exp_f32 (base-2) directly
#define QSCALE 0.18033688011112042f

#define GLDS16(g, l)                                                     \
    __builtin_amdgcn_global_load_lds(                                    \
        (const __attribute__((address_space(1))) void*)(g),              \
        (__attribute__((address_space(3))) void*)(l), 16, 0, 0)

// Partial drains: wave waits until at most N of ITS vmem ops remain.
#define WAIT_VM(n) asm volatile("s_waitcnt vmcnt(" #n ")" ::: "memory")

// ---------------- fp32 -> fp16 conversion ----------------
__global__ __launch_bounds__(256) void cvt_x(const float* __restrict__ in,
                                             f16_t* __restrict__ out, int n) {
    int i = (blockIdx.x * 256 + threadIdx.x) * 4;
    if (i + 3 < n) {
        float4 v = *(const float4*)&in[i];
        alignas(8) f16_t o4[4] = {(f16_t)v.x, (f16_t)v.y, (f16_t)v.z, (f16_t)v.w};
        *(uint2*)&out[i] = *(const uint2*)o4;
    }
}

// all 4 weights in one launch; Wq gets QSCALE folded in
__global__ __launch_bounds__(256) void cvt_w4(const float* __restrict__ w0,
                                              const float* __restrict__ w1,
                                              const float* __restrict__ w2,
                                              const float* __restrict__ w3,
                                              f16_t* __restrict__ out) {
    const int q = blockIdx.y;
    const float* src = (q == 0) ? w0 : (q == 1) ? w1 : (q == 2) ? w2 : w3;
    const float scale = (q == 0) ? QSCALE : 1.f;
    int i = (blockIdx.x * 256 + threadIdx.x) * 4;
    float4 v = *(const float4*)&src[i];
    alignas(8) f16_t o4[4] = {(f16_t)(v.x * scale), (f16_t)(v.y * scale),
                              (f16_t)(v.z * scale), (f16_t)(v.w * scale)};
    *(uint2*)&out[(size_t)q * (D_MODEL * D_MODEL) + i] = *(const uint2*)o4;
}

// ---------------- fp16 GEMM: C = A @ B^T ----------------
// Tile 128x128, BK=32, 4 waves. Triple-buffered fragment-major LDS staging,
// prefetch depth 2, vmcnt(4) partial drains. MFMA computes C^T (operands
// swapped: A/B frags have identical reg layouts) so regs hold consecutive
// N-cols -> packed f16x4/f32x4 epilogue stores (16 insts vs 64 scalar).
// mode 0: out f16 head-split [(col>>6)][M][64]; mode 1: out fp32 [M][N]
__global__ __launch_bounds__(256, 3) void gemm_f16(const f16_t* __restrict__ A,
                                                   const f16_t* __restrict__ B,
                                                   void* __restrict__ Cout,
                                                   int M, int N, int K, int mode) {
    __shared__ alignas(16) f16_t As[3][128 * 32];
    __shared__ alignas(16) f16_t Bs[3][128 * 32];

    const int tid  = threadIdx.x;
    const int wave = tid >> 6;
    const int lane = tid & 63;
    const int quad = lane >> 4;
    const int l16  = lane & 15;
    const int wm = (wave & 1) * 64;
    const int wn = (wave >> 1) * 64;
    const int bm = blockIdx.x * 128;
    const int bn = blockIdx.y * 128;

    f32x4 acc[4][4] = {};
    const int nk = K / 32;

    auto stage = [&](int kt, int b) {  // 4 GLDS per wave
        const int c0 = wave * 2;
        GLDS16(&A[(size_t)(bm + c0 * 16 + l16) * K + kt * 32 + quad * 8],
               &As[b][c0 * 512]);
        GLDS16(&A[(size_t)(bm + (c0 + 1) * 16 + l16) * K + kt * 32 + quad * 8],
               &As[b][(c0 + 1) * 512]);
        GLDS16(&B[(size_t)(bn + c0 * 16 + l16) * K + kt * 32 + quad * 8],
               &Bs[b][c0 * 512]);
        GLDS16(&B[(size_t)(bn + (c0 + 1) * 16 + l16) * K + kt * 32 + quad * 8],
               &Bs[b][(c0 + 1) * 512]);
    };

    stage(0, 0);
    stage(1, 1);
    for (int kt = 0; kt < nk; ++kt) {
        const int cb = kt % 3;
        if (kt < nk - 1) WAIT_VM(4);   // stage(kt) landed; kt+1 keeps flying
        else             WAIT_VM(0);
        __syncthreads();
        if (kt + 2 < nk) stage(kt + 2, (kt + 2) % 3);

        f16x8 af[4], bfr[4];
#pragma unroll
        for (int mt = 0; mt < 4; ++mt)
            af[mt] = *(const f16x8*)&As[cb][((wm >> 4) + mt) * 512 + lane * 8];
#pragma unroll
        for (int nt = 0; nt < 4; ++nt)
            bfr[nt] = *(const f16x8*)&Bs[cb][((wn >> 4) + nt) * 512 + lane * 8];
        // D = C^T: bfr as A-operand (m=col_C), af as B-operand (n=row_C)
#pragma unroll
        for (int mt = 0; mt < 4; ++mt)
#pragma unroll
            for (int nt = 0; nt < 4; ++nt)
                acc[mt][nt] = __builtin_amdgcn_mfma_f32_16x16x32_f16(
                    bfr[nt], af[mt], acc[mt][nt], 0, 0, 0);
    }

    // epilogue: lane holds row = ..+l16, cols = ..+quad*4+r (reg-consecutive)
#pragma unroll
    for (int mt = 0; mt < 4; ++mt)
#pragma unroll
        for (int nt = 0; nt < 4; ++nt) {
            int row = bm + wm + mt * 16 + l16;
            int col = bn + wn + nt * 16 + quad * 4;
            if (mode == 0) {
                f16x4 p = {(f16_t)acc[mt][nt][0], (f16_t)acc[mt][nt][1],
                           (f16_t)acc[mt][nt][2], (f16_t)acc[mt][nt][3]};
                *(f16x4*)&((f16_t*)Cout)[((size_t)(col >> 6) * M + row) * 64 +
                                         (col & 63)] = p;
            } else {
                *(f32x4*)&((float*)Cout)[(size_t)row * N + col] = acc[mt][nt];
            }
        }
}

// ---------------- V transpose: vh[H][L][64] -> vt[H][64][L] ----------------
__global__ __launch_bounds__(256) void transpose_v(const f16_t* __restrict__ vh,
                                                   f16_t* __restrict__ vt) {
    __shared__ f16_t Ts[64][72];
    const int t = threadIdx.x;
    const int lt = blockIdx.x;
    const int head = blockIdx.y;

#pragma unroll
    for (int i = 0; i < 2; ++i) {
        int idx = t + i * 256;
        int row = idx >> 3, part = idx & 7;
        *(uint4*)&Ts[row][part * 8] =
            *(const uint4*)&vh[((size_t)head * LSEQ + lt * 64 + row) * DH + part * 8];
    }
    __syncthreads();
#pragma unroll
    for (int i = 0; i < 2; ++i) {
        int idx = t + i * 256;
        int d = idx >> 3, part = idx & 7;
        alignas(16) f16_t p8[8];
#pragma unroll
        for (int j = 0; j < 8; ++j) p8[j] = Ts[part * 8 + j][d];
        *(uint4*)&vt[((size_t)head * DH + d) * LSEQ + lt * 64 + part * 8] =
            *(const uint4*)p8;
    }
}

// ---------------- attention ----------------
// qh/kh: [NH][L][64] f16 (Q pre-scaled), vt: [NH][64][L] f16, ao: [L][1024] f16
// In-block split-K: 512 threads = 8 waves; waves 0-3 keys [0,2048), waves 4-7
// keys [2048,4096), same 256 q-rows (64/wave). No softmax max-tracking -> o,l
// are pure sums -> merge halves through LDS at the end. 8 waves/CU.
// Ps uses XOR swizzle (key ^ ((qrow&7)<<3)) instead of padding: b64 stores
// 2-way banked (free), b128 reads uniform, slice = 8KB/wave -> fits 8 waves.
__global__ __launch_bounds__(512, 2) void attn_kernel(const f16_t* __restrict__ qh,
                                                      const f16_t* __restrict__ kh,
                                                      const f16_t* __restrict__ vt,
                                                      f16_t* __restrict__ ao) {
    __shared__ alignas(16) f16_t Ks[2][2][8 * 512];  // [khalf][buf][chunk]
    __shared__ alignas(16) f16_t Vs[2][2][8 * 512];
    __shared__ alignas(16) f16_t Ps[8 * 4096];       // per-wave swizzled P^T

    const int tid  = threadIdx.x;
    const int wave = tid >> 6;        // 0..7
    const int lane = tid & 63;
    const int quad = lane >> 4;
    const int l16  = lane & 15;
    const int wq   = wave & 3;        // q sub-panel within block
    const int kha  = wave >> 2;       // key half

    // head = id&15: all 16 q-panel blocks of a head land on XCD (head%8)
    const int id = blockIdx.x;
    const int head = id & 15;
    const int qrow0 = (id >> 4) * 256 + wq * 64;
    const int key0 = kha * (LSEQ / 2);

    const f16_t* Q  = qh + (size_t)head * LSEQ * DH;
    const f16_t* K  = kh + (size_t)head * LSEQ * DH;
    const f16_t* Vt = vt + (size_t)head * DH * LSEQ;

    f16x8 qf[4][2];
#pragma unroll
    for (int qt = 0; qt < 4; ++qt)
#pragma unroll
        for (int kc = 0; kc < 2; ++kc)
            qf[qt][kc] = *(const f16x8*)
                &Q[(size_t)(qrow0 + qt * 16 + l16) * DH + kc * 32 + quad * 8];

    f32x4 o[4][4] = {};
    float lp[4] = {0.f, 0.f, 0.f, 0.f};

    auto stage = [&](int kt, int b) {  // 4 GLDS per wave, into this half's bufs
        const int j0 = wq * 2;
#pragma unroll
        for (int jj = 0; jj < 2; ++jj) {
            const int j = j0 + jj, mt = j >> 1, kc = j & 1;
            GLDS16(&K[(size_t)(key0 + kt * 64 + mt * 16 + l16) * DH + kc * 32 +
                      quad * 8],
                   &Ks[kha][b][j * 512]);
            GLDS16(&Vt[(size_t)(mt * 16 + l16) * LSEQ + key0 + kt * 64 + kc * 32 +
                       quad * 8],
                   &Vs[kha][b][j * 512]);
        }
    };

    const int NT = LSEQ / 2 / 64;  // 32 tiles per half
    stage(0, 0);
    for (int kt = 0; kt < NT; ++kt) {
        const int cb = kt & 1;
        WAIT_VM(0);        // this wave's stage(kt) drained
        __syncthreads();   // all waves' staging visible; prev reads complete
        if (kt + 1 < NT) stage(kt + 1, cb ^ 1);  // flies during compute below

        f16x8 kf[4][2], vf[4][2];
#pragma unroll
        for (int mt = 0; mt < 4; ++mt)
#pragma unroll
            for (int kc = 0; kc < 2; ++kc)
                kf[mt][kc] = *(const f16x8*)&Ks[kha][cb][(mt * 2 + kc) * 512 +
                                                         lane * 8];
#pragma unroll
        for (int dt = 0; dt < 4; ++dt)
#pragma unroll
            for (int kc = 0; kc < 2; ++kc)
                vf[dt][kc] = *(const f16x8*)&Vs[kha][cb][(dt * 2 + kc) * 512 +
                                                         lane * 8];

        // S^T = K_tile . Q^T : D[m=key][n=qrow], 32 MFMA
        f32x4 s[4][4] = {};
#pragma unroll
        for (int mt = 0; mt < 4; ++mt)
#pragma unroll
            for (int qt = 0; qt < 4; ++qt)
#pragma unroll
                for (int kc = 0; kc < 2; ++kc)
                    s[mt][qt] = __builtin_amdgcn_mfma_f32_16x16x32_f16(
                        kf[mt][kc], qf[qt][kc], s[mt][qt], 0, 0, 0);

        // exp2, partial row sums, pack P^T with XOR-swizzled key index
#pragma unroll
        for (int mt = 0; mt < 4; ++mt)
#pragma unroll
            for (int qt = 0; qt < 4; ++qt) {
                float e0 = __builtin_amdgcn_exp2f(s[mt][qt][0]);
                float e1 = __builtin_amdgcn_exp2f(s[mt][qt][1]);
                float e2 = __builtin_amdgcn_exp2f(s[mt][qt][2]);
                float e3 = __builtin_amdgcn_exp2f(s[mt][qt][3]);
                lp[qt] += (e0 + e1) + (e2 + e3);
                f16x4 p = {(f16_t)e0, (f16_t)e1, (f16_t)e2, (f16_t)e3};
                int qr = qt * 16 + l16;
                int key2 = (mt * 16 + quad * 4) ^ ((qr & 7) << 3);
                *(f16x4*)&Ps[wave * 4096 + qr * 64 + key2] = p;
            }
        __builtin_amdgcn_wave_barrier();  // per-wave DS in-order (R2/R5-proven)

        f16x8 pf[4][2];
#pragma unroll
        for (int qt = 0; qt < 4; ++qt)
#pragma unroll
            for (int kc = 0; kc < 2; ++kc) {
                int qr = qt * 16 + l16;
                int keys = (kc * 32 + quad * 8) ^ ((qr & 7) << 3);
                pf[qt][kc] = *(const f16x8*)&Ps[wave * 4096 + qr * 64 + keys];
            }

        // O^T += V^T . P^T, 32 MFMA
#pragma unroll
        for (int dt = 0; dt < 4; ++dt)
#pragma unroll
            for (int qt = 0; qt < 4; ++qt)
#pragma unroll
                for (int kc = 0; kc < 2; ++kc)
                    o[dt][qt] = __builtin_amdgcn_mfma_f32_16x16x32_f16(
                        vf[dt][kc], pf[qt][kc], o[dt][qt], 0, 0, 0);
        __builtin_amdgcn_wave_barrier();  // next-iter Ps stores stay behind reads
    }

    // ---- merge the two key-halves (pure sums; no rescaling needed) ----
    __syncthreads();                    // everyone done with Ps/Vs
    float* scr  = (float*)Ps;           // 64 slots x 64 lanes x f32x4 = 64KB
    float* lscr = (float*)Vs;           // 16 x 64 f32 = 4KB
    if (wave >= 4) {
#pragma unroll
        for (int dt = 0; dt < 4; ++dt)
#pragma unroll
            for (int qt = 0; qt < 4; ++qt)
                *(f32x4*)&scr[(((wave - 4) * 16 + dt * 4 + qt) * 64 + lane) * 4] =
                    o[dt][qt];
#pragma unroll
        for (int qt = 0; qt < 4; ++qt)
            lscr[((wave - 4) * 4 + qt) * 64 + lane] = lp[qt];
    }
    __syncthreads();
    if (wave < 4) {
#pragma unroll
        for (int dt = 0; dt < 4; ++dt)
#pragma unroll
            for (int qt = 0; qt < 4; ++qt)
                o[dt][qt] += *(const f32x4*)
                    &scr[((wave * 16 + dt * 4 + qt) * 64 + lane) * 4];
#pragma unroll
        for (int qt = 0; qt < 4; ++qt) {
            float t = lp[qt] + lscr[(wave * 4 + qt) * 64 + lane];
            t += __shfl_xor(t, 16, 64);
            t += __shfl_xor(t, 32, 64);
            lp[qt] = 1.f / t;
        }
#pragma unroll
        for (int dt = 0; dt < 4; ++dt)
#pragma unroll
            for (int qt = 0; qt < 4; ++qt) {
                f16x4 ov = {(f16_t)(o[dt][qt][0] * lp[qt]),
                            (f16_t)(o[dt][qt][1] * lp[qt]),
                            (f16_t)(o[dt][qt][2] * lp[qt]),
                            (f16_t)(o[dt][qt][3] * lp[qt])};
                int qrow = qrow0 + qt * 16 + l16;
                *(f16x4*)&ao[(size_t)qrow * D_MODEL + head * 64 + dt * 16 +
                             quad * 4] = ov;
            }
    }
}

extern "C" void kernel_launch(void* const* d_in, const int* in_sizes, int n_in,
                              void* d_out, int out_size, void* d_ws, size_t ws_size,
                              hipStream_t stream) {
    const float* x  = (const float*)d_in[0];
    const float* Wq = (const float*)d_in[1];
    const float* Wk = (const float*)d_in[2];
    const float* Wv = (const float*)d_in[3];
    const float* Wo = (const float*)d_in[4];

    f16_t* xb = (f16_t*)d_ws;                        // [4096][1024]
    f16_t* wq = xb + (size_t)LSEQ * D_MODEL;         // [3072][1024] qkv concat
    f16_t* wo = wq + (size_t)3 * D_MODEL * D_MODEL;  // [1024][1024]
    f16_t* qh = wo + (size_t)D_MODEL * D_MODEL;      // [16][4096][64]
    f16_t* kh = qh + (size_t)LSEQ * D_MODEL;
    f16_t* vh = kh + (size_t)LSEQ * D_MODEL;
    f16_t* vt = vh + (size_t)LSEQ * D_MODEL;         // [16][64][4096]
    f16_t* ao = vt + (size_t)LSEQ * D_MODEL;         // [4096][1024]

    const int nx = LSEQ * D_MODEL;
    cvt_x<<<nx / 1024, 256, 0, stream>>>(x, xb, nx);
    cvt_w4<<<dim3(D_MODEL * D_MODEL / 1024, 4), 256, 0, stream>>>(Wq, Wk, Wv, Wo, wq);

    // fused QKV projection: [4096][1024] @ [3072][1024]^T -> head-split qh|kh|vh
    gemm_f16<<<dim3(LSEQ / 128, 3 * D_MODEL / 128), 256, 0, stream>>>(
        xb, wq, qh, LSEQ, 3 * D_MODEL, D_MODEL, 0);

    transpose_v<<<dim3(LSEQ / 64, NH), 256, 0, stream>>>(vh, vt);

    attn_kernel<<<dim3((LSEQ / 256) * NH), 512, 0, stream>>>(qh, kh, vt, ao);

    gemm_f16<<<dim3(LSEQ / 128, D_MODEL / 128), 256, 0, stream>>>(
        ao, wo, d_out, LSEQ, D_MODEL, D_MODEL, 1);
}

// Round 10
// 259.136 us; speedup vs baseline: 1.1737x; 1.0024x over previous
//
#include <hip/hip_runtime.h>

typedef _Float16 f16_t;
typedef __fp16 fp16x2 __attribute__((ext_vector_type(2)));
typedef _Float16 f16x2 __attribute__((ext_vector_type(2)));
typedef _Float16 f16x4 __attribute__((ext_vector_type(4)));
typedef _Float16 f16x8 __attribute__((ext_vector_type(8)));
typedef float f32x4 __attribute__((ext_vector_type(4)));

#define D_MODEL 1024
#define LSEQ 4096
#define NH 16
#define DH 64
// (1/sqrt(64)) * log2(e), folded into Wq so scores feed v_exp_f32 (base-2) directly
#define QSCALE 0.18033688011112042f

#define GLDS16(g, l)                                                     \
    __builtin_amdgcn_global_load_lds(                                    \
        (const __attribute__((address_space(1))) void*)(g),              \
        (__attribute__((address_space(3))) void*)(l), 16, 0, 0)

#define WAIT_VM(n) asm volatile("s_waitcnt vmcnt(" #n ")" ::: "memory")

// ---------------- fp32 -> fp16 conversion ----------------
__global__ __launch_bounds__(256) void cvt_x(const float* __restrict__ in,
                                             f16_t* __restrict__ out, int n) {
    int i = (blockIdx.x * 256 + threadIdx.x) * 4;
    if (i + 3 < n) {
        float4 v = *(const float4*)&in[i];
        alignas(8) f16_t o4[4] = {(f16_t)v.x, (f16_t)v.y, (f16_t)v.z, (f16_t)v.w};
        *(uint2*)&out[i] = *(const uint2*)o4;
    }
}

// all 4 weights in one launch; Wq gets QSCALE folded in
__global__ __launch_bounds__(256) void cvt_w4(const float* __restrict__ w0,
                                              const float* __restrict__ w1,
                                              const float* __restrict__ w2,
                                              const float* __restrict__ w3,
                                              f16_t* __restrict__ out) {
    const int q = blockIdx.y;
    const float* src = (q == 0) ? w0 : (q == 1) ? w1 : (q == 2) ? w2 : w3;
    const float scale = (q == 0) ? QSCALE : 1.f;
    int i = (blockIdx.x * 256 + threadIdx.x) * 4;
    float4 v = *(const float4*)&src[i];
    alignas(8) f16_t o4[4] = {(f16_t)(v.x * scale), (f16_t)(v.y * scale),
                              (f16_t)(v.z * scale), (f16_t)(v.w * scale)};
    *(uint2*)&out[(size_t)q * (D_MODEL * D_MODEL) + i] = *(const uint2*)o4;
}

// ---------------- fp16 GEMM: C = A @ B^T (unchanged from R7) ----------------
__global__ __launch_bounds__(256, 3) void gemm_f16(const f16_t* __restrict__ A,
                                                   const f16_t* __restrict__ B,
                                                   void* __restrict__ Cout,
                                                   int M, int N, int K, int mode) {
    __shared__ alignas(16) f16_t As[3][128 * 32];
    __shared__ alignas(16) f16_t Bs[3][128 * 32];

    const int tid  = threadIdx.x;
    const int wave = tid >> 6;
    const int lane = tid & 63;
    const int quad = lane >> 4;
    const int l16  = lane & 15;
    const int wm = (wave & 1) * 64;
    const int wn = (wave >> 1) * 64;
    const int bm = blockIdx.x * 128;
    const int bn = blockIdx.y * 128;

    f32x4 acc[4][4] = {};
    const int nk = K / 32;

    auto stage = [&](int kt, int b) {
        const int c0 = wave * 2;
        GLDS16(&A[(size_t)(bm + c0 * 16 + l16) * K + kt * 32 + quad * 8],
               &As[b][c0 * 512]);
        GLDS16(&A[(size_t)(bm + (c0 + 1) * 16 + l16) * K + kt * 32 + quad * 8],
               &As[b][(c0 + 1) * 512]);
        GLDS16(&B[(size_t)(bn + c0 * 16 + l16) * K + kt * 32 + quad * 8],
               &Bs[b][c0 * 512]);
        GLDS16(&B[(size_t)(bn + (c0 + 1) * 16 + l16) * K + kt * 32 + quad * 8],
               &Bs[b][(c0 + 1) * 512]);
    };

    stage(0, 0);
    stage(1, 1);
    for (int kt = 0; kt < nk; ++kt) {
        const int cb = kt % 3;
        if (kt < nk - 1) WAIT_VM(4);
        else             WAIT_VM(0);
        __syncthreads();
        if (kt + 2 < nk) stage(kt + 2, (kt + 2) % 3);

        f16x8 af[4], bfr[4];
#pragma unroll
        for (int mt = 0; mt < 4; ++mt)
            af[mt] = *(const f16x8*)&As[cb][((wm >> 4) + mt) * 512 + lane * 8];
#pragma unroll
        for (int nt = 0; nt < 4; ++nt)
            bfr[nt] = *(const f16x8*)&Bs[cb][((wn >> 4) + nt) * 512 + lane * 8];
#pragma unroll
        for (int mt = 0; mt < 4; ++mt)
#pragma unroll
            for (int nt = 0; nt < 4; ++nt)
                acc[mt][nt] = __builtin_amdgcn_mfma_f32_16x16x32_f16(
                    bfr[nt], af[mt], acc[mt][nt], 0, 0, 0);
    }

#pragma unroll
    for (int mt = 0; mt < 4; ++mt)
#pragma unroll
        for (int nt = 0; nt < 4; ++nt) {
            int row = bm + wm + mt * 16 + l16;
            int col = bn + wn + nt * 16 + quad * 4;
            if (mode == 0) {
                f16x4 p = {(f16_t)acc[mt][nt][0], (f16_t)acc[mt][nt][1],
                           (f16_t)acc[mt][nt][2], (f16_t)acc[mt][nt][3]};
                *(f16x4*)&((f16_t*)Cout)[((size_t)(col >> 6) * M + row) * 64 +
                                         (col & 63)] = p;
            } else {
                *(f32x4*)&((float*)Cout)[(size_t)row * N + col] = acc[mt][nt];
            }
        }
}

// ---------------- V fragmenting: vh[H][L][64] -> v4 (x16 A-operand image) ----
// v4 per head, per 64-key tile kt: 16 chunks (c = dt*4+kb) of 256 f16.
// Chunk element e: d = dt*16 + ((e>>2)&15), key = kt*64 + kb*16 + (e>>6)*4 + (e&3).
// In attn, lane reads b64 at chunk+lane*4: j-th f16 = V^T[d=l16][key=quad*4+j]
// == exact 16x16x16 A-operand fragment.
__global__ __launch_bounds__(256) void transpose_v(const f16_t* __restrict__ vh,
                                                   f16_t* __restrict__ v4) {
    __shared__ f16_t Ts[64][72];
    const int t = threadIdx.x;
    const int lt = blockIdx.x;
    const int head = blockIdx.y;

#pragma unroll
    for (int i = 0; i < 2; ++i) {
        int idx = t + i * 256;
        int row = idx >> 3, part = idx & 7;
        *(uint4*)&Ts[row][part * 8] =
            *(const uint4*)&vh[((size_t)head * LSEQ + lt * 64 + row) * DH + part * 8];
    }
    __syncthreads();

    const int c   = t >> 4;          // chunk 0..15
    const int dt  = c >> 2, kb = c & 3;
    const int km2 = (t & 15) >> 2;   // key bits 3..2
    const int dl2 = t & 3;           // d bits 3..2
    alignas(16) f16_t buf[16];
#pragma unroll
    for (int i = 0; i < 16; ++i) {
        int j = i & 3, dd = i >> 2;
        buf[i] = Ts[kb * 16 + km2 * 4 + j][dt * 16 + dl2 * 4 + dd];
    }
    f16_t* dst = v4 + (size_t)head * (LSEQ * DH) + lt * 4096 + c * 256 + (t & 15) * 16;
    *(uint4*)&dst[0] = *(const uint4*)&buf[0];
    *(uint4*)&dst[8] = *(const uint4*)&buf[8];
}

// ---------------- attention ----------------
// qh/kh: [NH][L][64] f16 (Q pre-scaled), v4: fragmented V (above), ao: [L][1024]
// In-block split-K (8 waves: 4 q-panels x 2 key-halves). PV uses
// mfma_f32_16x16x16f16 whose B-layout == S^T's C-layout -> exp'd scores feed PV
// directly from registers: NO P LDS round-trip, no wave barriers.
__global__ __launch_bounds__(512, 2) void attn_kernel(const f16_t* __restrict__ qh,
                                                      const f16_t* __restrict__ kh,
                                                      const f16_t* __restrict__ v4,
                                                      f16_t* __restrict__ ao) {
    // smem: Ks = [0,16K) f16, Vs = [16K,32K) f16; merge reuses all 64KB as f32
    __shared__ alignas(16) f16_t smem[32768];
    __shared__ alignas(16) float lscr[16 * 64];
    f16_t* KsB = smem;          // [kha][buf][4096]
    f16_t* VsB = smem + 16384;  // [kha][buf][4096]

    const int tid  = threadIdx.x;
    const int wave = tid >> 6;        // 0..7
    const int lane = tid & 63;
    const int quad = lane >> 4;
    const int l16  = lane & 15;
    const int wq   = wave & 3;        // q sub-panel
    const int kha  = wave >> 2;       // key half

    const int id = blockIdx.x;
    const int head = id & 15;         // 16 blocks/head share an XCD (head%8)
    const int qrow0 = (id >> 4) * 256 + wq * 64;

    const f16_t* Q  = qh + (size_t)head * LSEQ * DH;
    const f16_t* K  = kh + (size_t)head * LSEQ * DH;
    const f16_t* V4 = v4 + (size_t)head * (LSEQ * DH);

    f16x8 qf[4][2];
#pragma unroll
    for (int qt = 0; qt < 4; ++qt)
#pragma unroll
        for (int kc = 0; kc < 2; ++kc)
            qf[qt][kc] = *(const f16x8*)
                &Q[(size_t)(qrow0 + qt * 16 + l16) * DH + kc * 32 + quad * 8];

    f32x4 o[4][4] = {};
    float lp[4] = {0.f, 0.f, 0.f, 0.f};

    auto stage = [&](int kt, int b) {  // 4 GLDS per wave
        f16_t* ks = KsB + (kha * 2 + b) * 4096;
        f16_t* vs = VsB + (kha * 2 + b) * 4096;
        const int ktg = kha * 32 + kt;  // global 64-key tile index
#pragma unroll
        for (int jj = 0; jj < 2; ++jj) {
            const int j = wq * 2 + jj;               // K chunk: mt=wq, kc=jj
            GLDS16(&K[(size_t)(ktg * 64 + wq * 16 + l16) * DH + jj * 32 + quad * 8],
                   &ks[j * 512]);
            // V: pure memcpy of the pre-fragmented image
            GLDS16(&V4[(size_t)ktg * 4096 + wq * 1024 + jj * 512 + lane * 8],
                   &vs[wq * 1024 + jj * 512]);
        }
    };

    const int NT = LSEQ / 2 / 64;  // 32 tiles per half
    stage(0, 0);
    for (int kt = 0; kt < NT; ++kt) {
        const int cb = kt & 1;
        WAIT_VM(0);
        __syncthreads();
        if (kt + 1 < NT) stage(kt + 1, cb ^ 1);

        const f16_t* ks = KsB + (kha * 2 + cb) * 4096;
        const f16_t* vs = VsB + (kha * 2 + cb) * 4096;

#pragma unroll
        for (int mt = 0; mt < 4; ++mt) {
            f16x8 kf0 = *(const f16x8*)&ks[(mt * 2 + 0) * 512 + lane * 8];
            f16x8 kf1 = *(const f16x8*)&ks[(mt * 2 + 1) * 512 + lane * 8];

            // S^T block: D[m=key(16)][n=qrow], keys mt*16..+16
            f32x4 s[4] = {};
#pragma unroll
            for (int qt = 0; qt < 4; ++qt) {
                s[qt] = __builtin_amdgcn_mfma_f32_16x16x32_f16(kf0, qf[qt][0],
                                                               s[qt], 0, 0, 0);
                s[qt] = __builtin_amdgcn_mfma_f32_16x16x32_f16(kf1, qf[qt][1],
                                                               s[qt], 0, 0, 0);
            }

            // V^T fragments for this key sub-tile (x16 A-operand layout)
            f16x4 vfd[4];
#pragma unroll
            for (int dt = 0; dt < 4; ++dt)
                vfd[dt] = *(const f16x4*)&vs[(dt * 4 + mt) * 256 + lane * 4];

#pragma unroll
            for (int qt = 0; qt < 4; ++qt) {
                float e0 = __builtin_amdgcn_exp2f(s[qt][0]);
                float e1 = __builtin_amdgcn_exp2f(s[qt][1]);
                float e2 = __builtin_amdgcn_exp2f(s[qt][2]);
                float e3 = __builtin_amdgcn_exp2f(s[qt][3]);
                lp[qt] += (e0 + e1) + (e2 + e3);
                fp16x2 p01 = __builtin_amdgcn_cvt_pkrtz(e0, e1);
                fp16x2 p23 = __builtin_amdgcn_cvt_pkrtz(e2, e3);
                f16x4 p = {__builtin_bit_cast(f16x2, p01)[0],
                           __builtin_bit_cast(f16x2, p01)[1],
                           __builtin_bit_cast(f16x2, p23)[0],
                           __builtin_bit_cast(f16x2, p23)[1]};
                // O^T += V^T . P^T : x16 MFMA, B=p straight from registers
#pragma unroll
                for (int dt = 0; dt < 4; ++dt)
                    o[dt][qt] = __builtin_amdgcn_mfma_f32_16x16x16f16(
                        vfd[dt], p, o[dt][qt], 0, 0, 0);
            }
        }
    }

    // ---- merge the two key-halves (pure sums) ----
    __syncthreads();
    float* scr = (float*)smem;   // 64 KB
    if (wave >= 4) {
#pragma unroll
        for (int dt = 0; dt < 4; ++dt)
#pragma unroll
            for (int qt = 0; qt < 4; ++qt)
                *(f32x4*)&scr[(((wave - 4) * 16 + dt * 4 + qt) * 64 + lane) * 4] =
                    o[dt][qt];
#pragma unroll
        for (int qt = 0; qt < 4; ++qt)
            lscr[((wave - 4) * 4 + qt) * 64 + lane] = lp[qt];
    }
    __syncthreads();
    if (wave < 4) {
#pragma unroll
        for (int dt = 0; dt < 4; ++dt)
#pragma unroll
            for (int qt = 0; qt < 4; ++qt)
                o[dt][qt] += *(const f32x4*)
                    &scr[((wave * 16 + dt * 4 + qt) * 64 + lane) * 4];
#pragma unroll
        for (int qt = 0; qt < 4; ++qt) {
            float t = lp[qt] + lscr[(wave * 4 + qt) * 64 + lane];
            t += __shfl_xor(t, 16, 64);
            t += __shfl_xor(t, 32, 64);
            lp[qt] = 1.f / t;
        }
#pragma unroll
        for (int dt = 0; dt < 4; ++dt)
#pragma unroll
            for (int qt = 0; qt < 4; ++qt) {
                f16x4 ov = {(f16_t)(o[dt][qt][0] * lp[qt]),
                            (f16_t)(o[dt][qt][1] * lp[qt]),
                            (f16_t)(o[dt][qt][2] * lp[qt]),
                            (f16_t)(o[dt][qt][3] * lp[qt])};
                int qrow = qrow0 + qt * 16 + l16;
                *(f16x4*)&ao[(size_t)qrow * D_MODEL + head * 64 + dt * 16 +
                             quad * 4] = ov;
            }
    }
}

extern "C" void kernel_launch(void* const* d_in, const int* in_sizes, int n_in,
                              void* d_out, int out_size, void* d_ws, size_t ws_size,
                              hipStream_t stream) {
    const float* x  = (const float*)d_in[0];
    const float* Wq = (const float*)d_in[1];
    const float* Wk = (const float*)d_in[2];
    const float* Wv = (const float*)d_in[3];
    const float* Wo = (const float*)d_in[4];

    f16_t* xb = (f16_t*)d_ws;                        // [4096][1024]
    f16_t* wq = xb + (size_t)LSEQ * D_MODEL;         // [3072][1024] qkv concat
    f16_t* wo = wq + (size_t)3 * D_MODEL * D_MODEL;  // [1024][1024]
    f16_t* qh = wo + (size_t)D_MODEL * D_MODEL;      // [16][4096][64]
    f16_t* kh = qh + (size_t)LSEQ * D_MODEL;
    f16_t* vh = kh + (size_t)LSEQ * D_MODEL;
    f16_t* v4 = vh + (size_t)LSEQ * D_MODEL;         // fragmented V
    f16_t* ao = v4 + (size_t)LSEQ * D_MODEL;         // [4096][1024]

    const int nx = LSEQ * D_MODEL;
    cvt_x<<<nx / 1024, 256, 0, stream>>>(x, xb, nx);
    cvt_w4<<<dim3(D_MODEL * D_MODEL / 1024, 4), 256, 0, stream>>>(Wq, Wk, Wv, Wo, wq);

    gemm_f16<<<dim3(LSEQ / 128, 3 * D_MODEL / 128), 256, 0, stream>>>(
        xb, wq, qh, LSEQ, 3 * D_MODEL, D_MODEL, 0);

    transpose_v<<<dim3(LSEQ / 64, NH), 256, 0, stream>>>(vh, v4);

    attn_kernel<<<dim3((LSEQ / 256) * NH), 512, 0, stream>>>(qh, kh, v4, ao);

    gemm_f16<<<dim3(LSEQ / 128, D_MODEL / 128), 256, 0, stream>>>(
        ao, wo, d_out, LSEQ, D_MODEL, D_MODEL, 1);
}